// Round 10
// baseline (84.191 us; speedup 1.0000x reference)
//
#include <hip/hip_runtime.h>

// ============================================================================
// ROUND 10: ATTRIBUTION RUN. Kernels are byte-identical to round 9.
// kernel_launch fires proj x1 + attn x3 (attn is idempotent). With r9's
// P + A = 39.1us, total T = P + 3A  =>  A = (T - 39.1)/2.
// ============================================================================

#define HW 4096

typedef float f32x4 __attribute__((ext_vector_type(4)));
typedef __bf16 bf16x8 __attribute__((ext_vector_type(8)));
typedef unsigned short u16x8 __attribute__((ext_vector_type(8)));

union F8 { bf16x8 v; unsigned long long q[2]; unsigned short u[8]; __bf16 h[8]; };

__device__ inline unsigned short f2bf(float f) {
    unsigned int u = __builtin_bit_cast(unsigned int, f);
    u += 0x7fffu + ((u >> 16) & 1u);   // RNE
    return (unsigned short)(u >> 16);
}
__device__ inline float bf2f(unsigned short h) {
    unsigned int u = ((unsigned int)h) << 16;
    return __builtin_bit_cast(float, u);
}
__device__ inline bf16x8 frag_lo(const unsigned short* p) {
    F8 f; f.q[0] = *(const unsigned long long*)p; f.q[1] = 0ull; return f.v;
}

#define MFMA16(a,b,c) __builtin_amdgcn_mfma_f32_16x16x32_bf16(a, b, c, 0, 0, 0)
#define EXP2(x) __builtin_amdgcn_exp2f(x)

// ---------------------------------------------------------------------------
// Kernel 1: projections — byte-identical to round 9.
// ---------------------------------------------------------------------------
__global__ __launch_bounds__(256, 4) void proj_kernel(
    const float* __restrict__ x,
    const float* __restrict__ Wq, const float* __restrict__ bq,
    const float* __restrict__ Wk, const float* __restrict__ bk,
    const float* __restrict__ Wv, const float* __restrict__ bv,
    unsigned short* __restrict__ qbuf, unsigned short* __restrict__ kbuf,
    unsigned short* __restrict__ vtbuf)
{
    const float A2 = 0.51006977f;      // log2(e)/sqrt(8), folded into q
    __shared__ float ldsW[80][64];     // rows: 0..7 Wq*A2, 8..15 Wk, 16..79 Wv
    __shared__ float ldsB[80];

    const int blk   = blockIdx.x;
    const int b     = blk >> 8;
    const int rest  = blk & 255;
    const int ntile = rest >> 2;
    const int rg    = rest & 3;
    const int tid   = threadIdx.x;
    const int w     = tid >> 6;
    const int lane  = tid & 63;
    const int n     = ntile * 64 + lane;

    // issue x loads FIRST (independent of LDS) — latency hides under staging
    const float* xb = x + (size_t)b * 64 * HW + n;
    float xv[64];
#pragma unroll
    for (int c = 0; c < 64; ++c) xv[c] = xb[c * HW];

    // stage W: 5120 floats = 1280 f32x4, 256 threads x 5
#pragma unroll
    for (int kk = 0; kk < 5; ++kk) {
        const int idx = tid + kk * 256;          // f32x4 slot 0..1279
        const int r   = idx >> 4;                // row 0..79
        const int c   = (idx & 15) << 2;         // col 0,4,..,60
        f32x4 val;
        if (r < 8) { val = *(const f32x4*)(Wq + r * 64 + c); val *= A2; }
        else if (r < 16) val = *(const f32x4*)(Wk + (r - 8) * 64 + c);
        else             val = *(const f32x4*)(Wv + (r - 16) * 64 + c);
        *(f32x4*)(&ldsW[r][c]) = val;
    }
    if (tid < 80) {
        float bb = (tid < 8) ? bq[tid] * A2
                 : (tid < 16) ? bk[tid - 8] : bv[tid - 16];
        ldsB[tid] = bb;
    }
    __syncthreads();

    auto rowdot = [&](int row) -> float {
        const float* wr = &ldsW[row][0];
        float a0 = 0.f, a1 = 0.f, a2 = 0.f, a3 = 0.f;
#pragma unroll
        for (int c4 = 0; c4 < 16; ++c4) {
            f32x4 wv = *(const f32x4*)(wr + c4 * 4);   // uniform broadcast
            a0 = fmaf(wv[0], xv[c4*4+0], a0);
            a1 = fmaf(wv[1], xv[c4*4+1], a1);
            a2 = fmaf(wv[2], xv[c4*4+2], a2);
            a3 = fmaf(wv[3], xv[c4*4+3], a3);
        }
        return (a0 + a1) + (a2 + a3) + ldsB[row];
    };

    // fragment-major v address for pixel n (within one c-row of one batch)
    const int vaddr = ((n >> 5) << 5) + (((n >> 2) & 3) << 3)
                    + (n & 3) + (((n >> 4) & 1) << 2);

    const int r0 = rg * 20 + w * 5;
#pragma unroll
    for (int rr = 0; rr < 5; ++rr) {
        const int row = r0 + rr;            // wave-uniform
        float val = rowdot(row);
        if (row < 8) {
            unsigned short* qr = qbuf + (size_t)(b * HW + n) * 16;
            qr[row] = f2bf(val);
            qr[row + 8] = 0;
        } else if (row < 16) {
            unsigned short* kr = kbuf + (size_t)(b * HW + n) * 16;
            kr[row - 8] = f2bf(val);
            kr[row] = 0;
        } else {
            vtbuf[(size_t)b * 64 * HW + (size_t)(row - 16) * HW + vaddr] = f2bf(val);
        }
    }
}

// ---------------------------------------------------------------------------
// Kernel 2: attention + skip — byte-identical to round 9.
// ---------------------------------------------------------------------------
__global__ __launch_bounds__(512, 2) void attn_kernel(
    const unsigned short* __restrict__ qbuf,
    const unsigned short* __restrict__ kbuf,
    const unsigned short* __restrict__ vtbuf,
    const float* __restrict__ x,
    const float* __restrict__ gamma,
    float* __restrict__ out)
{
    const int blk  = blockIdx.x;
    const int slot = blk & 7;              // XCD slot = (b, c-half)
    const int qt   = blk >> 3;             // 0..63
    const int b    = slot >> 1;
    const int ct   = slot & 1;
    const int nb   = qt * 64;
    const int c0   = ct * 32;
    const int tid  = threadIdx.x;
    const int w    = tid >> 6;             // 0..7 = m-slice
    const int lane = tid & 63;
    const int g    = lane >> 4;
    const int ln   = lane & 15;

    __shared__ unsigned short ldsO[8][64][34];   // bf16 partials, padded
    __shared__ float ldsL[8][64];

    F8 zf; zf.q[0] = 0ull; zf.q[1] = 0ull;       // zero fragment (g>=1 pads)

    // Q B-frags for 4 query subtiles: only g=0 lanes carry data
    bf16x8 qf[4];
#pragma unroll
    for (int i = 0; i < 4; ++i)
        qf[i] = (g == 0)
              ? frag_lo(qbuf + (size_t)(b * HW + nb + 16 * i + ln) * 16)
              : zf.v;

    F8 onesu;
#pragma unroll
    for (int e = 0; e < 8; ++e) onesu.u[e] = 0x3F80;   // bf16 1.0
    const bf16x8 ones = onesu.v;

    f32x4 o[4][2], ol[4];
#pragma unroll
    for (int i = 0; i < 4; ++i) {
        o[i][0] = (f32x4){0,0,0,0};
        o[i][1] = (f32x4){0,0,0,0};
        ol[i]   = (f32x4){0,0,0,0};
    }

    const int mq = w * 512;                // this wave's m-slice
    const unsigned short* kb = kbuf + (size_t)(b * HW + mq + ln) * 16;
    const unsigned short* vb = vtbuf + (size_t)b * 64 * HW
                             + (size_t)(c0 + ln) * HW + mq + 8 * g;

#pragma unroll 2
    for (int ch = 0; ch < 16; ++ch) {
        const unsigned short* kp = kb + ch * 512;   // 32 K-rows x 16 ushorts
        bf16x8 kf0 = (g == 0) ? frag_lo(kp)       : zf.v;
        bf16x8 kf1 = (g == 0) ? frag_lo(kp + 256) : zf.v;
        const unsigned short* vp = vb + ch * 32;
        bf16x8 vf0 = *(const bf16x8*)(vp);           // c rows c0+ln
        bf16x8 vf1 = *(const bf16x8*)(vp + 16 * HW); // c rows c0+16+ln

        const f32x4 z = {0.f, 0.f, 0.f, 0.f};
#pragma unroll
        for (int i = 0; i < 4; ++i) {
            f32x4 s0 = MFMA16(kf0, qf[i], z);
            f32x4 s1 = MFMA16(kf1, qf[i], z);
            F8 pa;
#pragma unroll
            for (int r = 0; r < 4; ++r) {
                pa.h[r]     = (__bf16)EXP2(s0[r]);
                pa.h[r + 4] = (__bf16)EXP2(s1[r]);
            }
            __builtin_amdgcn_s_setprio(1);
            o[i][0] = MFMA16(pa.v, vf0, o[i][0]);
            o[i][1] = MFMA16(pa.v, vf1, o[i][1]);
            ol[i]   = MFMA16(pa.v, ones, ol[i]);
            __builtin_amdgcn_s_setprio(0);
        }
    }

    // stash partials: q = 16i + 4g + r, c-col = ln (+16)
#pragma unroll
    for (int i = 0; i < 4; ++i) {
#pragma unroll
        for (int r = 0; r < 4; ++r) {
            ldsO[w][16 * i + 4 * g + r][ln]      = f2bf(o[i][0][r]);
            ldsO[w][16 * i + 4 * g + r][16 + ln] = f2bf(o[i][1][r]);
        }
    }
    if (ln == 0) {
#pragma unroll
        for (int i = 0; i < 4; ++i)
#pragma unroll
            for (int r = 0; r < 4; ++r)
                ldsL[w][16 * i + 4 * g + r] = ol[i][r];
    }
    __syncthreads();

    // merge 8 m-slice partials; fused epilogue out = gamma*(O/L) + x
    const int q  = tid & 63;
    const int c8 = tid >> 6;               // 0..7
    float L = 0.f;
#pragma unroll
    for (int wv = 0; wv < 8; ++wv) L += ldsL[wv][q];
    const float inv = 1.0f / L;
    const float gm  = gamma[0];
#pragma unroll
    for (int j = 0; j < 4; ++j) {
        const int c = c8 + 8 * j;          // 0..31
        float Ov = 0.f;
#pragma unroll
        for (int wv = 0; wv < 8; ++wv) Ov += bf2f(ldsO[wv][q][c]);
        const size_t idx = (size_t)(b * 64 + c0 + c) * HW + nb + q;
        out[idx] = fmaf(gm, Ov * inv, x[idx]);
    }
}

extern "C" void kernel_launch(void* const* d_in, const int* in_sizes, int n_in,
                              void* d_out, int out_size, void* d_ws, size_t ws_size,
                              hipStream_t stream) {
    const float* x  = (const float*)d_in[0];
    const float* Wq = (const float*)d_in[1];
    const float* bq = (const float*)d_in[2];
    const float* Wk = (const float*)d_in[3];
    const float* bk = (const float*)d_in[4];
    const float* Wv = (const float*)d_in[5];
    const float* bv = (const float*)d_in[6];
    const float* gm = (const float*)d_in[7];

    // ws layout: qbuf 512KB | kbuf 512KB | vtbuf 2MB  (total 3MB)
    unsigned short* qbuf  = (unsigned short*)d_ws;
    unsigned short* kbuf  = qbuf + 4 * HW * 16;
    unsigned short* vtbuf = kbuf + 4 * HW * 16;
    float* out = (float*)d_out;

    proj_kernel<<<1024, 256, 0, stream>>>(x, Wq, bq, Wk, bk, Wv, bv,
                                          qbuf, kbuf, vtbuf);
    // ATTRIBUTION: attn launched 3x (idempotent — reads ws/x, writes out).
    // T = P + 3A; with r9's P + A = 39.1us  =>  A = (T - 39.1) / 2.
    attn_kernel<<<512, 512, 0, stream>>>(qbuf, kbuf, vtbuf, x, gm, out);
    attn_kernel<<<512, 512, 0, stream>>>(qbuf, kbuf, vtbuf, x, gm, out);
    attn_kernel<<<512, 512, 0, stream>>>(qbuf, kbuf, vtbuf, x, gm, out);
}

// Round 11
// 39.427 us; speedup vs baseline: 2.1353x; 2.1353x over previous
//
#include <hip/hip_runtime.h>

#define HW 4096

typedef float f32x4 __attribute__((ext_vector_type(4)));
typedef __bf16 bf16x8 __attribute__((ext_vector_type(8)));
typedef unsigned short u16x8 __attribute__((ext_vector_type(8)));

union F8 { bf16x8 v; unsigned long long q[2]; unsigned short u[8]; __bf16 h[8]; };

__device__ inline unsigned short f2bf(float f) {
    unsigned int u = __builtin_bit_cast(unsigned int, f);
    u += 0x7fffu + ((u >> 16) & 1u);   // RNE
    return (unsigned short)(u >> 16);
}
__device__ inline float bf2f(unsigned short h) {
    unsigned int u = ((unsigned int)h) << 16;
    return __builtin_bit_cast(float, u);
}
__device__ inline bf16x8 frag_lo(const unsigned short* p) {
    F8 f; f.q[0] = *(const unsigned long long*)p; f.q[1] = 0ull; return f.v;
}

#define MFMA16(a,b,c) __builtin_amdgcn_mfma_f32_16x16x32_bf16(a, b, c, 0, 0, 0)
#define EXP2(x) __builtin_amdgcn_exp2f(x)

// ---------------------------------------------------------------------------
// Kernel 1: projections — EXACT r8 form (r5 structure + A2 fold, xv loads
// AFTER the staging sync). The r9 xv-hoist regressed 10 -> 16.6us
// (attribution r10); reverted.
// grid 1024 = 4 b x 64 ntiles x 4 rowgroups; block 256; 5 rows/thread.
// ---------------------------------------------------------------------------
__global__ __launch_bounds__(256, 4) void proj_kernel(
    const float* __restrict__ x,
    const float* __restrict__ Wq, const float* __restrict__ bq,
    const float* __restrict__ Wk, const float* __restrict__ bk,
    const float* __restrict__ Wv, const float* __restrict__ bv,
    unsigned short* __restrict__ qbuf, unsigned short* __restrict__ kbuf,
    unsigned short* __restrict__ vtbuf)
{
    const float A2 = 0.51006977f;      // log2(e)/sqrt(8), folded into q
    __shared__ float ldsW[80][64];     // rows: 0..7 Wq*A2, 8..15 Wk, 16..79 Wv
    __shared__ float ldsB[80];

    const int blk   = blockIdx.x;
    const int b     = blk >> 8;
    const int rest  = blk & 255;
    const int ntile = rest >> 2;
    const int rg    = rest & 3;
    const int tid   = threadIdx.x;
    const int w     = tid >> 6;
    const int lane  = tid & 63;
    const int n     = ntile * 64 + lane;

    // stage W: 5120 floats = 1280 f32x4, 256 threads x 5
#pragma unroll
    for (int kk = 0; kk < 5; ++kk) {
        const int idx = tid + kk * 256;          // f32x4 slot 0..1279
        const int r   = idx >> 4;                // row 0..79
        const int c   = (idx & 15) << 2;         // col 0,4,..,60
        f32x4 val;
        if (r < 8) { val = *(const f32x4*)(Wq + r * 64 + c); val *= A2; }
        else if (r < 16) val = *(const f32x4*)(Wk + (r - 8) * 64 + c);
        else             val = *(const f32x4*)(Wv + (r - 16) * 64 + c);
        *(f32x4*)(&ldsW[r][c]) = val;
    }
    if (tid < 80) {
        float bb = (tid < 8) ? bq[tid] * A2
                 : (tid < 16) ? bk[tid - 8] : bv[tid - 16];
        ldsB[tid] = bb;
    }
    __syncthreads();

    const float* xb = x + (size_t)b * 64 * HW + n;
    float xv[64];
#pragma unroll
    for (int c = 0; c < 64; ++c) xv[c] = xb[c * HW];

    auto rowdot = [&](int row) -> float {
        const float* wr = &ldsW[row][0];
        float a0 = 0.f, a1 = 0.f, a2 = 0.f, a3 = 0.f;
#pragma unroll
        for (int c4 = 0; c4 < 16; ++c4) {
            f32x4 wv = *(const f32x4*)(wr + c4 * 4);   // uniform broadcast
            a0 = fmaf(wv[0], xv[c4*4+0], a0);
            a1 = fmaf(wv[1], xv[c4*4+1], a1);
            a2 = fmaf(wv[2], xv[c4*4+2], a2);
            a3 = fmaf(wv[3], xv[c4*4+3], a3);
        }
        return (a0 + a1) + (a2 + a3) + ldsB[row];
    };

    // fragment-major v address for pixel n (within one c-row of one batch)
    const int vaddr = ((n >> 5) << 5) + (((n >> 2) & 3) << 3)
                    + (n & 3) + (((n >> 4) & 1) << 2);

    const int r0 = rg * 20 + w * 5;
#pragma unroll
    for (int rr = 0; rr < 5; ++rr) {
        const int row = r0 + rr;            // wave-uniform
        float val = rowdot(row);
        if (row < 8) {
            unsigned short* qr = qbuf + (size_t)(b * HW + n) * 16;
            qr[row] = f2bf(val);
            qr[row + 8] = 0;
        } else if (row < 16) {
            unsigned short* kr = kbuf + (size_t)(b * HW + n) * 16;
            kr[row - 8] = f2bf(val);
            kr[row] = 0;
        } else {
            vtbuf[(size_t)b * 64 * HW + (size_t)(row - 16) * HW + vaddr] = f2bf(val);
        }
    }
}

// ---------------------------------------------------------------------------
// Kernel 2: attention + skip, v6 = ILP attack on the ~16us latency stall
// (attribution r10: A=22.5us vs ~6us compute floor; TLP maxed at 16 waves/CU
// by VGPR, proven unhelpful in r5 -> per-wave ILP is the lever).
//   - explicit K-fragment prefetch: next chunk's K issued into named regs
//     BEFORE current chunk's S->exp->PV; L2 latency hides under compute.
//     (tail prefetch reads 512B past kbuf = start of vtbuf: in-ws, unused.)
//   - uniform +ko loads (g>=1 lanes read the zero pad; no exec-divergent phi)
//   - setprio dropped (8 toggles/chunk, never A/B'd positive here)
// Layout as r8/r9: swapped QK^T, sigma slot bijection, ones-MFMA L.
// Wave = 64q x 32c x 512m; grid 512 = qt(64) x slot(8)=(b,c-half)/XCD.
// ---------------------------------------------------------------------------
__global__ __launch_bounds__(512, 2) void attn_kernel(
    const unsigned short* __restrict__ qbuf,
    const unsigned short* __restrict__ kbuf,
    const unsigned short* __restrict__ vtbuf,
    const float* __restrict__ x,
    const float* __restrict__ gamma,
    float* __restrict__ out)
{
    const int blk  = blockIdx.x;
    const int slot = blk & 7;              // XCD slot = (b, c-half)
    const int qt   = blk >> 3;             // 0..63
    const int b    = slot >> 1;
    const int ct   = slot & 1;
    const int nb   = qt * 64;
    const int c0   = ct * 32;
    const int tid  = threadIdx.x;
    const int w    = tid >> 6;             // 0..7 = m-slice
    const int lane = tid & 63;
    const int g    = lane >> 4;
    const int ln   = lane & 15;
    const int ko   = g ? 8 : 0;            // k-frag offset: data | zero pad

    __shared__ unsigned short ldsO[8][64][34];   // bf16 partials, padded
    __shared__ float ldsL[8][64];

    // Q B-frags for 4 query subtiles (uniform loads; g>=1 = zero pad)
    bf16x8 qf[4];
#pragma unroll
    for (int i = 0; i < 4; ++i)
        qf[i] = frag_lo(qbuf + (size_t)(b * HW + nb + 16 * i + ln) * 16 + ko);

    F8 onesu;
#pragma unroll
    for (int e = 0; e < 8; ++e) onesu.u[e] = 0x3F80;   // bf16 1.0
    const bf16x8 ones = onesu.v;

    f32x4 o[4][2], ol[4];
#pragma unroll
    for (int i = 0; i < 4; ++i) {
        o[i][0] = (f32x4){0,0,0,0};
        o[i][1] = (f32x4){0,0,0,0};
        ol[i]   = (f32x4){0,0,0,0};
    }

    const int mq = w * 512;                // this wave's m-slice
    const unsigned short* kb = kbuf + (size_t)(b * HW + mq + ln) * 16 + ko;
    const unsigned short* vb = vtbuf + (size_t)b * 64 * HW
                             + (size_t)(c0 + ln) * HW + mq + 8 * g;

    // prefetch chunk 0's K fragments
    bf16x8 kc0 = frag_lo(kb);
    bf16x8 kc1 = frag_lo(kb + 256);

#pragma unroll 2
    for (int ch = 0; ch < 16; ++ch) {
        // issue NEXT chunk's K loads first (latency hides under this chunk)
        const unsigned short* kpn = kb + (ch + 1) * 512;
        bf16x8 kn0 = frag_lo(kpn);
        bf16x8 kn1 = frag_lo(kpn + 256);

        const unsigned short* vp = vb + ch * 32;
        bf16x8 vf0 = *(const bf16x8*)(vp);           // c rows c0+ln
        bf16x8 vf1 = *(const bf16x8*)(vp + 16 * HW); // c rows c0+16+ln

        const f32x4 z = {0.f, 0.f, 0.f, 0.f};
#pragma unroll
        for (int i = 0; i < 4; ++i) {
            f32x4 s0 = MFMA16(kc0, qf[i], z);
            f32x4 s1 = MFMA16(kc1, qf[i], z);
            F8 pa;
#pragma unroll
            for (int r = 0; r < 4; ++r) {
                pa.h[r]     = (__bf16)EXP2(s0[r]);
                pa.h[r + 4] = (__bf16)EXP2(s1[r]);
            }
            o[i][0] = MFMA16(pa.v, vf0, o[i][0]);
            o[i][1] = MFMA16(pa.v, vf1, o[i][1]);
            ol[i]   = MFMA16(pa.v, ones, ol[i]);
        }
        kc0 = kn0;
        kc1 = kn1;
    }

    // stash partials: q = 16i + 4g + r, c-col = ln (+16)
#pragma unroll
    for (int i = 0; i < 4; ++i) {
#pragma unroll
        for (int r = 0; r < 4; ++r) {
            ldsO[w][16 * i + 4 * g + r][ln]      = f2bf(o[i][0][r]);
            ldsO[w][16 * i + 4 * g + r][16 + ln] = f2bf(o[i][1][r]);
        }
    }
    if (ln == 0) {
#pragma unroll
        for (int i = 0; i < 4; ++i)
#pragma unroll
            for (int r = 0; r < 4; ++r)
                ldsL[w][16 * i + 4 * g + r] = ol[i][r];
    }
    __syncthreads();

    // merge 8 m-slice partials; fused epilogue out = gamma*(O/L) + x
    const int q  = tid & 63;
    const int c8 = tid >> 6;               // 0..7
    float L = 0.f;
#pragma unroll
    for (int wv = 0; wv < 8; ++wv) L += ldsL[wv][q];
    const float inv = 1.0f / L;
    const float gm  = gamma[0];
#pragma unroll
    for (int j = 0; j < 4; ++j) {
        const int c = c8 + 8 * j;          // 0..31
        float Ov = 0.f;
#pragma unroll
        for (int wv = 0; wv < 8; ++wv) Ov += bf2f(ldsO[wv][q][c]);
        const size_t idx = (size_t)(b * 64 + c0 + c) * HW + nb + q;
        out[idx] = fmaf(gm, Ov * inv, x[idx]);
    }
}

extern "C" void kernel_launch(void* const* d_in, const int* in_sizes, int n_in,
                              void* d_out, int out_size, void* d_ws, size_t ws_size,
                              hipStream_t stream) {
    const float* x  = (const float*)d_in[0];
    const float* Wq = (const float*)d_in[1];
    const float* bq = (const float*)d_in[2];
    const float* Wk = (const float*)d_in[3];
    const float* bk = (const float*)d_in[4];
    const float* Wv = (const float*)d_in[5];
    const float* bv = (const float*)d_in[6];
    const float* gm = (const float*)d_in[7];

    // ws layout: qbuf 512KB | kbuf 512KB | vtbuf 2MB  (total 3MB)
    unsigned short* qbuf  = (unsigned short*)d_ws;
    unsigned short* kbuf  = qbuf + 4 * HW * 16;
    unsigned short* vtbuf = kbuf + 4 * HW * 16;
    float* out = (float*)d_out;

    proj_kernel<<<1024, 256, 0, stream>>>(x, Wq, bq, Wk, bk, Wv, bv,
                                          qbuf, kbuf, vtbuf);
    attn_kernel<<<512, 512, 0, stream>>>(qbuf, kbuf, vtbuf, x, gm, out);
}

// Round 12
// 33.448 us; speedup vs baseline: 2.5171x; 1.1788x over previous
//
#include <hip/hip_runtime.h>

#define HW 4096

typedef float f32x4 __attribute__((ext_vector_type(4)));
typedef __bf16 bf16x8 __attribute__((ext_vector_type(8)));
typedef unsigned short u16x8 __attribute__((ext_vector_type(8)));

union F8 { bf16x8 v; unsigned long long q[2]; unsigned short u[8]; __bf16 h[8]; };

__device__ inline unsigned short f2bf(float f) {
    unsigned int u = __builtin_bit_cast(unsigned int, f);
    u += 0x7fffu + ((u >> 16) & 1u);   // RNE
    return (unsigned short)(u >> 16);
}
__device__ inline float bf2f(unsigned short h) {
    unsigned int u = ((unsigned int)h) << 16;
    return __builtin_bit_cast(float, u);
}
__device__ inline bf16x8 frag_lo(const unsigned short* p) {
    F8 f; f.q[0] = *(const unsigned long long*)p; f.q[1] = 0ull; return f.v;
}

#define MFMA16(a,b,c) __builtin_amdgcn_mfma_f32_16x16x32_bf16(a, b, c, 0, 0, 0)
#define EXP2(x) __builtin_amdgcn_exp2f(x)

// ---------------------------------------------------------------------------
// Kernel 1: projections — r8/r11 structure (P~10us). Store-layout changes
// ONLY (for attn load coalescing):
//   qpack/kpack [b][n][8]  — 8 data ushorts, no zero pad (pad was never read)
//   vt3 [b][u=n>>5][c][32] — window-major so a wave's V-frag load is one
//                            contiguous 1KB region (16 lines vs 64 before).
// In-window slot = perm(n&31) = ((n>>2)&3)*8 + (n&3) + 4*((n>>4)&1), which
// equals the sigma slot bijection of the swapped-QK^T C-fragment (verified:
// perm(16h+4g+r) = 8g+4h+r = slot index 8g+j with j=4h+r).
// ---------------------------------------------------------------------------
__global__ __launch_bounds__(256, 4) void proj_kernel(
    const float* __restrict__ x,
    const float* __restrict__ Wq, const float* __restrict__ bq,
    const float* __restrict__ Wk, const float* __restrict__ bk,
    const float* __restrict__ Wv, const float* __restrict__ bv,
    unsigned short* __restrict__ qpack, unsigned short* __restrict__ kpack,
    unsigned short* __restrict__ vt3)
{
    const float A2 = 0.51006977f;      // log2(e)/sqrt(8), folded into q
    __shared__ float ldsW[80][64];     // rows: 0..7 Wq*A2, 8..15 Wk, 16..79 Wv
    __shared__ float ldsB[80];

    const int blk   = blockIdx.x;
    const int b     = blk >> 8;
    const int rest  = blk & 255;
    const int ntile = rest >> 2;
    const int rg    = rest & 3;
    const int tid   = threadIdx.x;
    const int w     = tid >> 6;
    const int lane  = tid & 63;
    const int n     = ntile * 64 + lane;

    // stage W: 5120 floats = 1280 f32x4, 256 threads x 5
#pragma unroll
    for (int kk = 0; kk < 5; ++kk) {
        const int idx = tid + kk * 256;          // f32x4 slot 0..1279
        const int r   = idx >> 4;                // row 0..79
        const int c   = (idx & 15) << 2;         // col 0,4,..,60
        f32x4 val;
        if (r < 8) { val = *(const f32x4*)(Wq + r * 64 + c); val *= A2; }
        else if (r < 16) val = *(const f32x4*)(Wk + (r - 8) * 64 + c);
        else             val = *(const f32x4*)(Wv + (r - 16) * 64 + c);
        *(f32x4*)(&ldsW[r][c]) = val;
    }
    if (tid < 80) {
        float bb = (tid < 8) ? bq[tid] * A2
                 : (tid < 16) ? bk[tid - 8] : bv[tid - 16];
        ldsB[tid] = bb;
    }
    __syncthreads();

    const float* xb = x + (size_t)b * 64 * HW + n;
    float xv[64];
#pragma unroll
    for (int c = 0; c < 64; ++c) xv[c] = xb[c * HW];

    auto rowdot = [&](int row) -> float {
        const float* wr = &ldsW[row][0];
        float a0 = 0.f, a1 = 0.f, a2 = 0.f, a3 = 0.f;
#pragma unroll
        for (int c4 = 0; c4 < 16; ++c4) {
            f32x4 wv = *(const f32x4*)(wr + c4 * 4);   // uniform broadcast
            a0 = fmaf(wv[0], xv[c4*4+0], a0);
            a1 = fmaf(wv[1], xv[c4*4+1], a1);
            a2 = fmaf(wv[2], xv[c4*4+2], a2);
            a3 = fmaf(wv[3], xv[c4*4+3], a3);
        }
        return (a0 + a1) + (a2 + a3) + ldsB[row];
    };

    // vt3 base for pixel n: window u = n>>5, slot = perm(n&31)
    const int vslot = (((n >> 2) & 3) << 3) + (n & 3) + (((n >> 4) & 1) << 2);
    unsigned short* vB = vt3 + ((size_t)(b * 128 + (n >> 5)) * 64) * 32 + vslot;

    const int r0 = rg * 20 + w * 5;
#pragma unroll
    for (int rr = 0; rr < 5; ++rr) {
        const int row = r0 + rr;            // wave-uniform
        float val = rowdot(row);
        if (row < 8) {
            qpack[(size_t)(b * HW + n) * 8 + row] = f2bf(val);
        } else if (row < 16) {
            kpack[(size_t)(b * HW + n) * 8 + (row - 8)] = f2bf(val);
        } else {
            vB[(size_t)(row - 16) * 32] = f2bf(val);
        }
    }
}

// ---------------------------------------------------------------------------
// Kernel 2: attention + skip, v7 = r9 inner structure (best measured A=22.5,
// per-i fused S->exp->PV, setprio, divergent g==0 frag loads) with COALESCED
// layouts. Diagnosis (r10 attribution + line counting): attn was L2
// line-request bound — V frag loads hit 64 lines/inst (c-stride 8KB, 25%
// utilization), K 32 lines/inst; ~12.6M lines ~= 23us ~= measured A. New:
//   V via vt3[b][u][c][32]: wave's vf0 = contiguous 1KB = 16 lines (4x cut)
//   K via kpack[b][n][8]: 16 active lanes x 8B contiguous = 2 lines (16x cut)
// Wave = 64q x 32c x 512m; grid 512 = qt(64) x slot(8)=(b,c-half)/XCD.
// ---------------------------------------------------------------------------
__global__ __launch_bounds__(512, 2) void attn_kernel(
    const unsigned short* __restrict__ qpack,
    const unsigned short* __restrict__ kpack,
    const unsigned short* __restrict__ vt3,
    const float* __restrict__ x,
    const float* __restrict__ gamma,
    float* __restrict__ out)
{
    const int blk  = blockIdx.x;
    const int slot = blk & 7;              // XCD slot = (b, c-half)
    const int qt   = blk >> 3;             // 0..63
    const int b    = slot >> 1;
    const int ct   = slot & 1;
    const int nb   = qt * 64;
    const int c0   = ct * 32;
    const int tid  = threadIdx.x;
    const int w    = tid >> 6;             // 0..7 = m-slice
    const int lane = tid & 63;
    const int g    = lane >> 4;
    const int ln   = lane & 15;

    __shared__ unsigned short ldsO[8][64][34];   // bf16 partials, padded
    __shared__ float ldsL[8][64];

    F8 zf; zf.q[0] = 0ull; zf.q[1] = 0ull;       // zero fragment (g>=1 pads)

    // Q B-frags for 4 query subtiles: only g=0 lanes carry data
    bf16x8 qf[4];
#pragma unroll
    for (int i = 0; i < 4; ++i)
        qf[i] = (g == 0)
              ? frag_lo(qpack + (size_t)(b * HW + nb + 16 * i + ln) * 8)
              : zf.v;

    F8 onesu;
#pragma unroll
    for (int e = 0; e < 8; ++e) onesu.u[e] = 0x3F80;   // bf16 1.0
    const bf16x8 ones = onesu.v;

    f32x4 o[4][2], ol[4];
#pragma unroll
    for (int i = 0; i < 4; ++i) {
        o[i][0] = (f32x4){0,0,0,0};
        o[i][1] = (f32x4){0,0,0,0};
        ol[i]   = (f32x4){0,0,0,0};
    }

    const int mq = w * 512;                // this wave's m-slice
    const unsigned short* kb = kpack + (size_t)(b * HW + mq + ln) * 8;
    // window-major V: wave w covers windows u = w*16 + ch
    const unsigned short* vwin = vt3 + ((size_t)b * 128 + w * 16) * 2048
                               + (c0 + ln) * 32 + 8 * g;

#pragma unroll 2
    for (int ch = 0; ch < 16; ++ch) {
        const unsigned short* kp = kb + ch * 256;    // 32 K-rows x 8 ushorts
        bf16x8 kf0 = (g == 0) ? frag_lo(kp)       : zf.v;
        bf16x8 kf1 = (g == 0) ? frag_lo(kp + 128) : zf.v;
        const unsigned short* vp = vwin + ch * 2048;
        bf16x8 vf0 = *(const bf16x8*)(vp);           // c rows c0+ln
        bf16x8 vf1 = *(const bf16x8*)(vp + 512);     // c rows c0+16+ln

        const f32x4 z = {0.f, 0.f, 0.f, 0.f};
#pragma unroll
        for (int i = 0; i < 4; ++i) {
            f32x4 s0 = MFMA16(kf0, qf[i], z);
            f32x4 s1 = MFMA16(kf1, qf[i], z);
            F8 pa;
#pragma unroll
            for (int r = 0; r < 4; ++r) {
                pa.h[r]     = (__bf16)EXP2(s0[r]);
                pa.h[r + 4] = (__bf16)EXP2(s1[r]);
            }
            __builtin_amdgcn_s_setprio(1);
            o[i][0] = MFMA16(pa.v, vf0, o[i][0]);
            o[i][1] = MFMA16(pa.v, vf1, o[i][1]);
            ol[i]   = MFMA16(pa.v, ones, ol[i]);
            __builtin_amdgcn_s_setprio(0);
        }
    }

    // stash partials: q = 16i + 4g + r, c-col = ln (+16)
#pragma unroll
    for (int i = 0; i < 4; ++i) {
#pragma unroll
        for (int r = 0; r < 4; ++r) {
            ldsO[w][16 * i + 4 * g + r][ln]      = f2bf(o[i][0][r]);
            ldsO[w][16 * i + 4 * g + r][16 + ln] = f2bf(o[i][1][r]);
        }
    }
    if (ln == 0) {
#pragma unroll
        for (int i = 0; i < 4; ++i)
#pragma unroll
            for (int r = 0; r < 4; ++r)
                ldsL[w][16 * i + 4 * g + r] = ol[i][r];
    }
    __syncthreads();

    // merge 8 m-slice partials; fused epilogue out = gamma*(O/L) + x
    const int q  = tid & 63;
    const int c8 = tid >> 6;               // 0..7
    float L = 0.f;
#pragma unroll
    for (int wv = 0; wv < 8; ++wv) L += ldsL[wv][q];
    const float inv = 1.0f / L;
    const float gm  = gamma[0];
#pragma unroll
    for (int j = 0; j < 4; ++j) {
        const int c = c8 + 8 * j;          // 0..31
        float Ov = 0.f;
#pragma unroll
        for (int wv = 0; wv < 8; ++wv) Ov += bf2f(ldsO[wv][q][c]);
        const size_t idx = (size_t)(b * 64 + c0 + c) * HW + nb + q;
        out[idx] = fmaf(gm, Ov * inv, x[idx]);
    }
}

extern "C" void kernel_launch(void* const* d_in, const int* in_sizes, int n_in,
                              void* d_out, int out_size, void* d_ws, size_t ws_size,
                              hipStream_t stream) {
    const float* x  = (const float*)d_in[0];
    const float* Wq = (const float*)d_in[1];
    const float* bq = (const float*)d_in[2];
    const float* Wk = (const float*)d_in[3];
    const float* bk = (const float*)d_in[4];
    const float* Wv = (const float*)d_in[5];
    const float* bv = (const float*)d_in[6];
    const float* gm = (const float*)d_in[7];

    // ws layout: qpack 256KB | kpack 256KB | vt3 2MB  (total 2.5MB)
    unsigned short* qpack = (unsigned short*)d_ws;
    unsigned short* kpack = qpack + 4 * HW * 8;
    unsigned short* vt3   = kpack + 4 * HW * 8;
    float* out = (float*)d_out;

    proj_kernel<<<1024, 256, 0, stream>>>(x, Wq, bq, Wk, bk, Wv, bv,
                                          qpack, kpack, vt3);
    attn_kernel<<<512, 512, 0, stream>>>(qpack, kpack, vt3, x, gm, out);
}